// Round 1
// baseline (312.035 us; speedup 1.0000x reference)
//
#include <hip/hip_runtime.h>
#include <math.h>

#define NCLS 80
#define BINS 16
#define BATCH 32
#define MAX_GT 32
#define NA 8400
#define ALPHA_C 0.25f
#define W_CLS 1.0
#define W_IOU 7.5
#define W_DFL 1.5
#define EPS_F 1e-7f

// acc layout (doubles): [0]=cls_sum [1]=iou_sum [2]=dfl_sum [3]=pos_count
__global__ __launch_bounds__(256) void yolo_loss_main(
    const float* __restrict__ p0, const float* __restrict__ p1, const float* __restrict__ p2,
    const float* __restrict__ gt_bboxes, const int* __restrict__ gt_labels,
    const int* __restrict__ matched, double* __restrict__ acc)
{
    const int a = blockIdx.x * blockDim.x + threadIdx.x;   // anchor id in [0, 8400)
    const int b = blockIdx.y;                              // batch id

    float cls_acc = 0.f, iou_acc = 0.f, dfl_acc = 0.f;
    int pos_cnt = 0;

    if (a < NA) {
        const float* p; int HW, W; float stride; int off;
        if (a < 6400)      { p = p0; HW = 6400; W = 80; stride = 8.f;  off = a; }
        else if (a < 8000) { p = p1; HW = 1600; W = 40; stride = 16.f; off = a - 6400; }
        else               { p = p2; HW = 400;  W = 20; stride = 32.f; off = a - 8000; }

        const int h = off / W;
        const int w = off - h * W;
        const float cx = ((float)w + 0.5f) * stride;
        const float cy = ((float)h + 0.5f) * stride;

        // base pointer for this (b, anchor): channel c lives at pb[c * HW]
        const float* pb = p + ((size_t)b * 144) * (size_t)HW + (size_t)off;

        const int m = matched[(size_t)b * NA + a];
        const bool pos = (m >= 0);
        const int idx = pos ? m : 0;
        const int lbl = gt_labels[b * MAX_GT + idx];
        const float* tbp = gt_bboxes + ((size_t)b * MAX_GT + idx) * 4;
        const float tx1 = tbp[0], ty1 = tbp[1], tx2 = tbp[2], ty2 = tbp[3];

        // target distances (in bin units)
        float tdist[4];
        tdist[0] = fmaxf(cx - tx1, 0.f) / stride;
        tdist[1] = fmaxf(cy - ty1, 0.f) / stride;
        tdist[2] = fmaxf(tx2 - cx, 0.f) / stride;
        tdist[3] = fmaxf(ty2 - cy, 0.f) / stride;

        float pdist[4];
        float dfl_sum = 0.f;

        #pragma unroll
        for (int k = 0; k < 4; ++k) {
            // DFL target bin pair (depends only on GT; compute before logits)
            float t = fminf(tdist[k], (float)(BINS - 1) - 1e-6f);
            int lo = (int)floorf(t);
            int hi = min(lo + 1, BINS - 1);
            float fr = t - (float)lo;

            const float* pc = pb + (size_t)(k * BINS) * HW;
            float v[BINS];
            #pragma unroll
            for (int i = 0; i < BINS; ++i) v[i] = pc[(size_t)i * HW];

            float mx = v[0];
            #pragma unroll
            for (int i = 1; i < BINS; ++i) mx = fmaxf(mx, v[i]);

            float se = 0.f, we = 0.f, vlo = 0.f, vhi = 0.f;
            #pragma unroll
            for (int i = 0; i < BINS; ++i) {
                float e = __expf(v[i] - mx);
                se += e;
                we += (float)i * e;
                vlo = (i == lo) ? v[i] : vlo;   // static index into v[] after unroll
                vhi = (i == hi) ? v[i] : vhi;
            }
            pdist[k] = (we / se) * stride;

            if (pos) {
                float lse = mx + __logf(se);
                dfl_sum += -((1.f - fr) * (vlo - lse) + fr * (vhi - lse));
            }
        }

        // classification focal-BCE over 80 classes (all anchors)
        const float* pcls = pb + (size_t)(4 * BINS) * HW;
        #pragma unroll 4
        for (int c = 0; c < NCLS; ++c) {
            float s = pcls[(size_t)c * HW];
            float tt = (pos && c == lbl) ? 1.f : 0.f;
            float e = __expf(-fabsf(s));
            float inv = 1.f / (1.f + e);
            float prob = (s >= 0.f) ? inv : e * inv;          // sigmoid(s)
            float ce = fmaxf(s, 0.f) - s * tt + __logf(1.f + e);
            float p_t = prob * tt + (1.f - prob) * (1.f - tt);
            float alpha_t = tt * ALPHA_C + (1.f - tt) * (1.f - ALPHA_C);
            float om = 1.f - p_t;
            cls_acc += alpha_t * om * om * ce;
        }

        if (pos) {
            float px1 = cx - pdist[0], py1 = cy - pdist[1];
            float px2 = cx + pdist[2], py2 = cy + pdist[3];
            float ix1 = fmaxf(px1, tx1), iy1 = fmaxf(py1, ty1);
            float ix2 = fminf(px2, tx2), iy2 = fminf(py2, ty2);
            float inter  = fmaxf(ix2 - ix1, 0.f) * fmaxf(iy2 - iy1, 0.f);
            float area_p = fmaxf(px2 - px1, 0.f) * fmaxf(py2 - py1, 0.f);
            float area_t = fmaxf(tx2 - tx1, 0.f) * fmaxf(ty2 - ty1, 0.f);
            float iou = inter / (area_p + area_t - inter + EPS_F);
            iou_acc = 1.f - iou;
            dfl_acc = dfl_sum;
            pos_cnt = 1;
        }
    }

    // wave (64-lane) shuffle reduction
    #pragma unroll
    for (int o = 32; o > 0; o >>= 1) {
        cls_acc += __shfl_down(cls_acc, o);
        iou_acc += __shfl_down(iou_acc, o);
        dfl_acc += __shfl_down(dfl_acc, o);
        pos_cnt += __shfl_down(pos_cnt, o);
    }

    __shared__ float s_cls[4], s_iou[4], s_dfl[4];
    __shared__ int   s_cnt[4];
    const int wave = threadIdx.x >> 6;
    const int lane = threadIdx.x & 63;
    if (lane == 0) { s_cls[wave] = cls_acc; s_iou[wave] = iou_acc; s_dfl[wave] = dfl_acc; s_cnt[wave] = pos_cnt; }
    __syncthreads();
    if (threadIdx.x == 0) {
        float bc = 0.f, bi = 0.f, bd = 0.f; int bn = 0;
        #pragma unroll
        for (int k = 0; k < 4; ++k) { bc += s_cls[k]; bi += s_iou[k]; bd += s_dfl[k]; bn += s_cnt[k]; }
        atomicAdd(&acc[0], (double)bc);
        atomicAdd(&acc[1], (double)bi);
        atomicAdd(&acc[2], (double)bd);
        atomicAdd(&acc[3], (double)bn);
    }
}

__global__ void yolo_loss_finalize(const double* __restrict__ acc, float* __restrict__ out)
{
    double np = acc[3] < 1.0 ? 1.0 : acc[3];
    double total = W_CLS * acc[0] / np + W_IOU * acc[1] / np + W_DFL * acc[2] / (np * 4.0);
    out[0] = (float)total;
}

extern "C" void kernel_launch(void* const* d_in, const int* in_sizes, int n_in,
                              void* d_out, int out_size, void* d_ws, size_t ws_size,
                              hipStream_t stream)
{
    const float* p0        = (const float*)d_in[0];
    const float* p1        = (const float*)d_in[1];
    const float* p2        = (const float*)d_in[2];
    const float* gt_bboxes = (const float*)d_in[3];
    const int*   gt_labels = (const int*)d_in[4];
    const int*   matched   = (const int*)d_in[5];
    float*  out = (float*)d_out;
    double* acc = (double*)d_ws;

    hipMemsetAsync(acc, 0, 4 * sizeof(double), stream);

    dim3 grid((NA + 255) / 256, BATCH);
    yolo_loss_main<<<grid, 256, 0, stream>>>(p0, p1, p2, gt_bboxes, gt_labels, matched, acc);
    yolo_loss_finalize<<<1, 1, 0, stream>>>(acc, out);
}